// Round 15
// baseline (41.851 us; speedup 1.0000x reference)
//
#include <hip/hip_runtime.h>

// DepthLossForImgBEV: weighted BCE over (B,N,D,H,W) depth logits vs one-hot
// bucketized GT depth, reduced to a scalar mean * 3.0.
//
// B=2 N=6 D=112 H=64 W=176.  depth: (B,N*D,H,W) f32 (60.6 MB, ~half
// L3-resident); depth_gt: (B,N,H,W) f32 (cache-hot).
//
// R11 measured: k1 ~= 12 us, k2 + dispatch gap ~= 7 us of R10's 20.56 best.
// Fused-kernel history: R3/R9/R12/R13 compiled to VGPR 16-44 (compiler sank
// loads into uses, serialized, ~650 GB/s). R14's asm-into-array blocked SROA:
// xv[] lived in SCRATCH (VGPR=40 < 64 needed), each asm result spill-stored
// with a wait -> still serial + 512B/thread scratch traffic.
//
// R15: named SSA f32x4 locals x0..x15 (never an array -> registers,
// provably: any spill needs >=64 VGPRs anyway and budget is 256) as outputs
// of 16 ORDERED asm volatile global_load_dwordx4 with no intervening uses
// (uses are what attract compiler waits), then ONE s_waitcnt vmcnt(0) +
// sched_barrier(0) (rule #18). 16 loads in flight by construction.
// Tail: R13's O(N) protocol -- non-finishers store partial + release flag and
// exit; block 0 polls <=4 flags/thread with s_sleep backoff, acquire-fences,
// reduces 924 partials in fixed order, writes out, clears flags for the next
// replay. Correct from any initial flag content (poison != MAGIC).

namespace {

typedef float f32x4 __attribute__((ext_vector_type(4)));

constexpr int B_ = 2, N_ = 6, D_ = 112, H_ = 64, W_ = 176;
constexpr int HW_   = H_ * W_;          // 11264
constexpr int NHWQ_ = HW_ / 4;          // 2816 float4 quads per image plane
constexpr int DPC_  = 16, NCH_ = 7;     // 7 d-chunks x 16 slices = 112
constexpr int NBN_  = B_ * N_;          // 12
constexpr long long TOT_ = (long long)NBN_ * D_ * HW_;   // 15,138,816
constexpr int NTHR_ = NBN_ * NCH_ * NHWQ_;               // 236,544
constexpr int NBLK_ = NTHR_ / 256;                       // 924 blocks
constexpr float SCALE_ = (float)(3.0 / (double)TOT_);    // 3.0 / numel
constexpr int MAGIC_ = 0x5A17ED0F;      // != 0, != 0xAAAAAAAA

// bce = min(softplus(+-x), 100) * w;  softplus(x) = relu(x) + log1p(exp(-|x|))
__device__ __forceinline__ float term(float x, float w, bool hit) {
    float c = __logf(1.0f + __expf(-fabsf(x)));          // shared log term
    float r = hit ? fmaxf(-x, 0.0f) : fmaxf(x, 0.0f);
    return w * fminf(c + r, 100.0f);
}

__device__ __forceinline__ int bucket(float g) {
    int i = (int)floorf((g - 2.0f) * 2.0f);   // (g - DBOUND0) / DBOUND2
    return i < 0 ? 0 : (i > D_ ? D_ : i);     // clip [0,D]; D never matches d
}

#define LOAD16(idx, dst) \
    asm volatile("global_load_dwordx4 %0, %1, off" \
                 : "=v"(dst) : "v"(p + (size_t)(idx) * HW_))

__global__ __launch_bounds__(256) void depth_loss_fused(
        const float* __restrict__ gt, const float* __restrict__ dp,
        float* __restrict__ part, int* __restrict__ flags,
        float* __restrict__ out) {
    const int t    = blockIdx.x * 256 + threadIdx.x;
    const int hwq  = t % NHWQ_;           // quad within image plane
    const int rest = t / NHWQ_;
    const int ch   = rest % NCH_;         // which 16-slice d-chunk
    const int bn   = rest / NCH_;         // (b*N + n)
    const int hw   = hwq * 4;
    const int d0   = ch * DPC_;

    const float4 g = *reinterpret_cast<const float4*>(gt + bn * HW_ + hw);
    const float* p = dp + ((bn * D_ + d0) * HW_ + hw);

    // 16 ordered asm loads into NAMED SSA f32x4s; no uses until the waitcnt.
    f32x4 x0, x1, x2, x3, x4, x5, x6, x7, x8, x9, xa, xb, xc, xd, xe, xf;
    LOAD16(0, x0);  LOAD16(1, x1);  LOAD16(2, x2);  LOAD16(3, x3);
    LOAD16(4, x4);  LOAD16(5, x5);  LOAD16(6, x6);  LOAD16(7, x7);
    LOAD16(8, x8);  LOAD16(9, x9);  LOAD16(10, xa); LOAD16(11, xb);
    LOAD16(12, xc); LOAD16(13, xd); LOAD16(14, xe); LOAD16(15, xf);
    asm volatile("s_waitcnt vmcnt(0)" ::: "memory");
    __builtin_amdgcn_sched_barrier(0);   // rule #18: no use-hoisting past the wait

    const float w0 = (g.x != 0.0f) ? 1.0f : 0.0f;
    const float w1 = (g.y != 0.0f) ? 1.0f : 0.0f;
    const float w2 = (g.z != 0.0f) ? 1.0f : 0.0f;
    const float w3 = (g.w != 0.0f) ? 1.0f : 0.0f;
    const int  i0 = bucket(g.x), i1 = bucket(g.y), i2 = bucket(g.z), i3 = bucket(g.w);

    float s = 0.0f;
#define TERM4(xi, dd) \
    s += term(xi[0], w0, (dd) == i0) + term(xi[1], w1, (dd) == i1) \
       + term(xi[2], w2, (dd) == i2) + term(xi[3], w3, (dd) == i3)
    TERM4(x0, d0+0);  TERM4(x1, d0+1);  TERM4(x2, d0+2);  TERM4(x3, d0+3);
    TERM4(x4, d0+4);  TERM4(x5, d0+5);  TERM4(x6, d0+6);  TERM4(x7, d0+7);
    TERM4(x8, d0+8);  TERM4(x9, d0+9);  TERM4(xa, d0+10); TERM4(xb, d0+11);
    TERM4(xc, d0+12); TERM4(xd, d0+13); TERM4(xe, d0+14); TERM4(xf, d0+15);
#undef TERM4

    // block reduce -> one partial per block
    #pragma unroll
    for (int off = 32; off > 0; off >>= 1) s += __shfl_down(s, off, 64);
    __shared__ float ls[4];
    if ((threadIdx.x & 63) == 0) ls[threadIdx.x >> 6] = s;
    __syncthreads();

    if (blockIdx.x != 0) {
        // publish partial, then flag; exit immediately (no scan traffic)
        if (threadIdx.x == 0) {
            __hip_atomic_store(&part[blockIdx.x], (ls[0] + ls[1]) + (ls[2] + ls[3]),
                               __ATOMIC_RELAXED, __HIP_MEMORY_SCOPE_AGENT);
            __hip_atomic_store(&flags[blockIdx.x], MAGIC_,
                               __ATOMIC_RELEASE, __HIP_MEMORY_SCOPE_AGENT);
        }
        return;
    }

    // ---- block 0: the only poller/finisher ----
    if (threadIdx.x == 0)
        part[0] = (ls[0] + ls[1]) + (ls[2] + ls[3]);

    for (;;) {   // poll own subset (<=4 flags/thread) until all peers published
        bool mine = true;
        for (int i = threadIdx.x; i < NBLK_; i += 256)
            if (i != 0)
                mine &= (__hip_atomic_load(&flags[i], __ATOMIC_RELAXED,
                                           __HIP_MEMORY_SCOPE_AGENT) == MAGIC_);
        if (__syncthreads_and(mine)) break;
        __builtin_amdgcn_s_sleep(8);     // backoff: keep coherent traffic low
    }
    __threadfence();   // acquire: order flag reads before partial reads

    float r = 0.0f;
    for (int i = threadIdx.x; i < NBLK_; i += 256)   // fixed-order -> deterministic
        r += (i == 0) ? part[0]
                      : __hip_atomic_load(&part[i], __ATOMIC_RELAXED,
                                          __HIP_MEMORY_SCOPE_AGENT);
    #pragma unroll
    for (int off = 32; off > 0; off >>= 1) r += __shfl_down(r, off, 64);
    if ((threadIdx.x & 63) == 0) ls[threadIdx.x >> 6] = r;
    __syncthreads();
    if (threadIdx.x == 0)
        out[0] = ((ls[0] + ls[1]) + (ls[2] + ls[3])) * SCALE_;

    // clear flags for the next replay (visible at kernel end)
    for (int i = threadIdx.x; i < NBLK_; i += 256)
        __hip_atomic_store(&flags[i], 0, __ATOMIC_RELAXED,
                           __HIP_MEMORY_SCOPE_AGENT);
}

}  // namespace

extern "C" void kernel_launch(void* const* d_in, const int* in_sizes, int n_in,
                              void* d_out, int out_size, void* d_ws, size_t ws_size,
                              hipStream_t stream) {
    const float* gt = (const float*)d_in[0];   // depth_gt (B,N,H,W)
    const float* dp = (const float*)d_in[1];   // depth (B,N*D,H,W)
    float* part = (float*)d_ws;                // 924 floats @ ws+0
    int* flags  = (int*)((char*)d_ws + 4096);  // 924 ints  @ ws+4096
    float* out  = (float*)d_out;
    depth_loss_fused<<<NBLK_, 256, 0, stream>>>(gt, dp, part, flags, out);
}

// Round 16
// 20.603 us; speedup vs baseline: 2.0313x; 2.0313x over previous
//
#include <hip/hip_runtime.h>

// DepthLossForImgBEV: weighted BCE over (B,N,D,H,W) depth logits vs one-hot
// bucketized GT depth, reduced to a scalar mean * 3.0.
//
// B=2 N=6 D=112 H=64 W=176.  depth: (B,N*D,H,W) f32 (60.6 MB, ~half
// L3-resident per FETCH_SIZE); depth_gt: (B,N,H,W) f32 (cache-hot).
//
// FINAL STRUCTURE (= R10, 20.56 us best). Two kernels:
//   k1 (924x256, xv[16] float4 batch): ~12 us = 60.6 MB at ~5.1 TB/s
//      effective read BW -- at the practical read-stream roofline (fills'
//      6.9 TB/s is write-only; copy ubench 6.29 TB/s is read+write).
//      Geometry-insensitive: R2/R4/R7/R10 = 20.6-22.0 across 4 shapes.
//   k2 (1 block): reduce 924 partials, scale, write scalar. k2+gap ~7 us,
//      fixed dispatch cost.
// Fusion to one dispatch is conclusively dead: 6 attempts (coop x2, ticket,
// flag-scan, block0-poll, asm-array, asm-SSA) all compiled to VGPR 16-44 --
// the backend spills/serializes the 16-deep load batch whenever the fused
// completion tail is present (35-130 us). Per-replay 4B memsets cost ~39 us
// as graph nodes; same-address atomics serialize (R0). Scratch partials need
// no init (overwritten each replay); out overwritten by k2 each replay.

namespace {

constexpr int B_ = 2, N_ = 6, D_ = 112, H_ = 64, W_ = 176;
constexpr int HW_   = H_ * W_;          // 11264
constexpr int NHWQ_ = HW_ / 4;          // 2816 float4 quads per image plane
constexpr int DPC_  = 16, NCH_ = 7;     // 7 d-chunks x 16 slices = 112
constexpr int NBN_  = B_ * N_;          // 12
constexpr long long TOT_ = (long long)NBN_ * D_ * HW_;   // 15,138,816
constexpr int NTHR_ = NBN_ * NCH_ * NHWQ_;               // 236,544
constexpr int NBLK_ = NTHR_ / 256;                       // 924 blocks
constexpr float SCALE_ = (float)(3.0 / (double)TOT_);    // 3.0 / numel

// bce = min(softplus(+-x), 100) * w;  softplus(x) = relu(x) + log1p(exp(-|x|))
__device__ __forceinline__ float term(float x, float w, bool hit) {
    float c = __logf(1.0f + __expf(-fabsf(x)));          // shared log term
    float r = hit ? fmaxf(-x, 0.0f) : fmaxf(x, 0.0f);
    return w * fminf(c + r, 100.0f);
}

__device__ __forceinline__ int bucket(float g) {
    int i = (int)floorf((g - 2.0f) * 2.0f);   // (g - DBOUND0) / DBOUND2
    return i < 0 ? 0 : (i > D_ ? D_ : i);     // clip [0,D]; D never matches d
}

__global__ __launch_bounds__(256) void depth_loss_part(
        const float* __restrict__ gt, const float* __restrict__ dp,
        float* __restrict__ part) {
    const int t    = blockIdx.x * 256 + threadIdx.x;
    const int hwq  = t % NHWQ_;           // quad within image plane
    const int rest = t / NHWQ_;
    const int ch   = rest % NCH_;         // which 16-slice d-chunk
    const int bn   = rest / NCH_;         // (b*N + n)
    const int hw   = hwq * 4;
    const int d0   = ch * DPC_;

    // issue gt + all 16 slice loads back-to-back
    const float4 g = *reinterpret_cast<const float4*>(gt + bn * HW_ + hw);
    const float* p = dp + ((bn * D_ + d0) * HW_ + hw);
    float4 xv[DPC_];
    #pragma unroll
    for (int i = 0; i < DPC_; ++i)
        xv[i] = *reinterpret_cast<const float4*>(p + (size_t)i * HW_);

    // keep-alive fence (R10-verified neutral-or-better; keeps loads batched)
    #pragma unroll
    for (int i = 0; i < DPC_; ++i)
        asm volatile("" :: "v"(xv[i].x), "v"(xv[i].y), "v"(xv[i].z), "v"(xv[i].w));

    const float w0 = (g.x != 0.0f) ? 1.0f : 0.0f;
    const float w1 = (g.y != 0.0f) ? 1.0f : 0.0f;
    const float w2 = (g.z != 0.0f) ? 1.0f : 0.0f;
    const float w3 = (g.w != 0.0f) ? 1.0f : 0.0f;
    const int  i0 = bucket(g.x), i1 = bucket(g.y), i2 = bucket(g.z), i3 = bucket(g.w);

    float s = 0.0f;
    #pragma unroll
    for (int i = 0; i < DPC_; ++i) {
        const int d = d0 + i;
        s += term(xv[i].x, w0, d == i0);
        s += term(xv[i].y, w1, d == i1);
        s += term(xv[i].z, w2, d == i2);
        s += term(xv[i].w, w3, d == i3);
    }

    // block reduce -> one partial per block (overwrite, no init needed)
    #pragma unroll
    for (int off = 32; off > 0; off >>= 1) s += __shfl_down(s, off, 64);
    __shared__ float ls[4];
    if ((threadIdx.x & 63) == 0) ls[threadIdx.x >> 6] = s;
    __syncthreads();
    if (threadIdx.x == 0)
        part[blockIdx.x] = (ls[0] + ls[1]) + (ls[2] + ls[3]);
}

__global__ __launch_bounds__(256) void depth_loss_final(
        const float* __restrict__ part, float* __restrict__ out) {
    float s = part[threadIdx.x] + part[threadIdx.x + 256] + part[threadIdx.x + 512];
    if (threadIdx.x + 768 < NBLK_) s += part[threadIdx.x + 768];
    #pragma unroll
    for (int off = 32; off > 0; off >>= 1) s += __shfl_down(s, off, 64);
    __shared__ float ls[4];
    if ((threadIdx.x & 63) == 0) ls[threadIdx.x >> 6] = s;
    __syncthreads();
    if (threadIdx.x == 0)
        out[0] = ((ls[0] + ls[1]) + (ls[2] + ls[3])) * SCALE_;
}

}  // namespace

extern "C" void kernel_launch(void* const* d_in, const int* in_sizes, int n_in,
                              void* d_out, int out_size, void* d_ws, size_t ws_size,
                              hipStream_t stream) {
    const float* gt = (const float*)d_in[0];   // depth_gt (B,N,H,W)
    const float* dp = (const float*)d_in[1];   // depth (B,N*D,H,W)
    float* part = (float*)d_ws;                // 924 floats of scratch
    float* out  = (float*)d_out;
    depth_loss_part<<<NBLK_, 256, 0, stream>>>(gt, dp, part);
    depth_loss_final<<<1, 256, 0, stream>>>(part, out);
}